// Round 3
// baseline (192.740 us; speedup 1.0000x reference)
//
#include <hip/hip_runtime.h>
#include <hip/hip_bf16.h>

#define BB 4096
#define VV 8
#define HH 512
#define RR 16
#define DKK 32
#define GHH 16
#define OUTD 512
#define TEMP 5.656854249492380195f   // sqrt(32)
#define EPSG 1e-10f

// Precompute k2[r][d] = rule_emb[r] @ Wk2[:,d] + bk2[d]   -> ws (f32, 16*32)
__global__ void k2_kernel(const float* __restrict__ rule_emb,
                          const float* __restrict__ Wk2,
                          const float* __restrict__ bk2,
                          float* __restrict__ k2) {
    int t = threadIdx.x;              // 512 threads
    int r = t >> 5, d = t & 31;
    float acc = bk2[d];
    for (int h = 0; h < 64; ++h)
        acc += rule_emb[r * 64 + h] * Wk2[h * 32 + d];
    k2[t] = acc;
}

__launch_bounds__(256)
__global__ void rulenet_kernel(const float* __restrict__ hidden,
                               const float* __restrict__ u_var,
                               const float* __restrict__ u_rule,
                               const float* __restrict__ Wq,
                               const float* __restrict__ bq,
                               const float* __restrict__ Wk,
                               const float* __restrict__ bk,
                               const float* __restrict__ Wq2,
                               const float* __restrict__ bq2,
                               const float* __restrict__ W1,
                               const float* __restrict__ W2,
                               const float* __restrict__ k2,
                               float* __restrict__ out) {
    const int b   = blockIdx.x;
    const int tid = threadIdx.x;

    __shared__ float s_hid[VV * HH];       // 16 KB, hidden[b]
    __shared__ float s_q[VV][DKK];
    __shared__ float s_k[VV][DKK];
    __shared__ float s_hmean[HH];
    __shared__ float s_part[8][DKK];
    __shared__ float s_q2[DKK];
    __shared__ float s_p1[16][GHH];
    __shared__ float s_h1[GHH];
    __shared__ int   s_sel;
    __shared__ int   s_rsel;

    // ---- 1. load hidden[b] (4096 f32) into LDS, float4 vectorized ----
    const float* hb = hidden + (size_t)b * (VV * HH);
    #pragma unroll
    for (int c = 0; c < 4; ++c) {
        int base = c * 1024 + tid * 4;
        float4 w = *reinterpret_cast<const float4*>(hb + base);
        *reinterpret_cast<float4*>(&s_hid[base]) = w;
    }
    __syncthreads();

    // ---- 1.5 h_mean ----
    for (int h = tid; h < HH; h += 256) {
        float s = 0.f;
        #pragma unroll
        for (int v = 0; v < VV; ++v) s += s_hid[v * HH + h];
        s_hmean[h] = s * 0.125f;
    }

    // ---- 2. q = hid@Wq+bq, k = hid@Wk+bk : one (v,d) output per thread ----
    {
        int v = tid >> 5, d = tid & 31;
        float aq = bq[d];
        float ak = bk[d];
        const float* hv = &s_hid[v * HH];
        for (int h = 0; h < HH; ++h) {
            float x = hv[h];
            aq += x * Wq[h * DKK + d];
            ak += x * Wk[h * DKK + d];
        }
        s_q[v][d] = aq;
        s_k[v][d] = ak;
    }
    __syncthreads();

    // ---- 3. scores + gumbel + 64-way argmax (wave 0) ----
    if (tid < 64) {
        int i = tid >> 3, j = tid & 7;
        float s = 0.f;
        #pragma unroll
        for (int d = 0; d < DKK; ++d) s += s_q[i][d] * s_k[j][d];
        s /= TEMP;
        float u = u_var[(size_t)b * 64 + tid];
        float g = -logf(-logf(u + EPSG) + EPSG);
        float p = s + g;
        int idx = tid;
        #pragma unroll
        for (int off = 32; off >= 1; off >>= 1) {
            float pv = __shfl_xor(p, off);
            int   pi = __shfl_xor(idx, off);
            if (pv > p || (pv == p && pi < idx)) { p = pv; idx = pi; }
        }
        if (tid == 0) s_sel = idx;
    }
    __syncthreads();
    const int msel = s_sel;
    const int isel = msel >> 3;   // context variable index (i)
    const int jsel = msel & 7;    // primary variable index (j)

    // ---- 4. q2 = concat(h_p, h_c, h_mean) @ Wq2 + bq2 ----
    {
        int d = tid & 31, seg = tid >> 5;           // 8 segments x 192 elems
        const float* hp = &s_hid[jsel * HH];
        const float* hc = &s_hid[isel * HH];
        float acc = 0.f;
        int t0 = seg * 192;
        for (int t = t0; t < t0 + 192; ++t) {
            float x = (t < 512) ? hp[t] : (t < 1024) ? hc[t - 512] : s_hmean[t - 1024];
            acc += x * Wq2[t * DKK + d];
        }
        s_part[seg][d] = acc;
    }
    __syncthreads();
    if (tid < 32) {
        float a = bq2[tid];
        #pragma unroll
        for (int s = 0; s < 8; ++s) a += s_part[s][tid];
        s_q2[tid] = a;
    }
    __syncthreads();

    // ---- 5. rule scores + gumbel + 16-way argmax (lanes 0..15) ----
    if (tid < 16) {
        float s = 0.f;
        #pragma unroll
        for (int d = 0; d < DKK; ++d) s += s_q2[d] * k2[tid * DKK + d];
        s /= TEMP;
        float u = u_rule[(size_t)b * 16 + tid];
        float g = -logf(-logf(u + EPSG) + EPSG);
        float p = s + g;
        int idx = tid;
        #pragma unroll
        for (int off = 8; off >= 1; off >>= 1) {
            float pv = __shfl_xor(p, off, 16);
            int   pi = __shfl_xor(idx, off, 16);
            if (pv > p || (pv == p && pi < idx)) { p = pv; idx = pi; }
        }
        if (tid == 0) s_rsel = idx;
    }
    __syncthreads();
    const int rsel = s_rsel;

    // ---- 6. h1 = relu(concat(h_p,h_c) @ W1[rsel]) ----
    {
        int e = tid & 15, seg = tid >> 4;           // 16 segments x 64 elems
        const float* hp = &s_hid[jsel * HH];
        const float* hc = &s_hid[isel * HH];
        const float* w1 = W1 + (size_t)rsel * 1024 * 16;
        float acc = 0.f;
        int t0 = seg * 64;
        for (int t = t0; t < t0 + 64; ++t) {
            float x = (t < 512) ? hp[t] : hc[t - 512];
            acc += x * w1[t * 16 + e];
        }
        s_p1[seg][e] = acc;
    }
    __syncthreads();
    if (tid < 16) {
        float a = 0.f;
        #pragma unroll
        for (int s = 0; s < 16; ++s) a += s_p1[s][tid];
        s_h1[tid] = fmaxf(a, 0.f);
    }
    __syncthreads();

    // ---- 7. rout = h1 @ W2[rsel]; scatter to slot v == jsel (f32 out) ----
    {
        const float* w2 = W2 + (size_t)rsel * 16 * 512;
        int o0 = tid * 2;
        float a0 = 0.f, a1 = 0.f;
        #pragma unroll
        for (int e = 0; e < GHH; ++e) {
            float h1e = s_h1[e];
            float2 ww = *reinterpret_cast<const float2*>(w2 + e * 512 + o0);
            a0 += h1e * ww.x;
            a1 += h1e * ww.y;
        }
        float2 nz = make_float2(a0, a1);
        float2 zz = make_float2(0.f, 0.f);
        float2* ob = reinterpret_cast<float2*>(out + (size_t)b * VV * OUTD);
        #pragma unroll
        for (int v = 0; v < VV; ++v) {
            ob[v * 256 + tid] = (v == jsel) ? nz : zz;
        }
    }
}

extern "C" void kernel_launch(void* const* d_in, const int* in_sizes, int n_in,
                              void* d_out, int out_size, void* d_ws, size_t ws_size,
                              hipStream_t stream) {
    const float* hidden   = (const float*)d_in[0];
    const float* u_var    = (const float*)d_in[1];
    const float* u_rule   = (const float*)d_in[2];
    const float* Wq       = (const float*)d_in[3];
    const float* bq       = (const float*)d_in[4];
    const float* Wk       = (const float*)d_in[5];
    const float* bk       = (const float*)d_in[6];
    const float* rule_emb = (const float*)d_in[7];
    const float* Wq2      = (const float*)d_in[8];
    const float* bq2      = (const float*)d_in[9];
    const float* Wk2      = (const float*)d_in[10];
    const float* bk2      = (const float*)d_in[11];
    const float* W1       = (const float*)d_in[12];
    const float* W2       = (const float*)d_in[13];

    float* k2 = (float*)d_ws;   // 16*32 f32

    hipLaunchKernelGGL(k2_kernel, dim3(1), dim3(512), 0, stream,
                       rule_emb, Wk2, bk2, k2);
    hipLaunchKernelGGL(rulenet_kernel, dim3(BB), dim3(256), 0, stream,
                       hidden, u_var, u_rule, Wq, bq, Wk, bk,
                       Wq2, bq2, W1, W2, k2, (float*)d_out);
}

// Round 4
// 185.258 us; speedup vs baseline: 1.0404x; 1.0404x over previous
//
#include <hip/hip_runtime.h>
#include <hip/hip_bf16.h>

#define TEMP 5.656854249492380195f   // sqrt(32)
#define EPSG 1e-10f

// Precompute k2[r][d] = rule_emb[r] @ Wk2[:,d] + bk2[d]   -> ws (f32, 16*32)
__global__ void k2_kernel(const float* __restrict__ rule_emb,
                          const float* __restrict__ Wk2,
                          const float* __restrict__ bk2,
                          float* __restrict__ k2) {
    int t = threadIdx.x;              // 512 threads
    int r = t >> 5, d = t & 31;
    float acc = bk2[d];
    for (int h = 0; h < 64; ++h)
        acc += rule_emb[r * 64 + h] * Wk2[h * 32 + d];
    k2[t] = acc;
}

__launch_bounds__(256, 4)
__global__ void rulenet_kernel(const float* __restrict__ hidden,
                               const float* __restrict__ u_var,
                               const float* __restrict__ u_rule,
                               const float* __restrict__ Wq,
                               const float* __restrict__ bq,
                               const float* __restrict__ Wk,
                               const float* __restrict__ bk,
                               const float* __restrict__ Wq2,
                               const float* __restrict__ bq2,
                               const float* __restrict__ W1,
                               const float* __restrict__ W2,
                               const float* __restrict__ k2,
                               float* __restrict__ out) {
    const int b   = blockIdx.x;
    const int tid = threadIdx.x;

    __shared__ float s_hid[4096];      // 16 KB, hidden[b]
    __shared__ float s_q[8][32];
    __shared__ float s_k[8][32];
    __shared__ float s_hmean[512];
    __shared__ float s_q2[32];
    __shared__ float s_h1[16];
    __shared__ int   s_sel;
    __shared__ int   s_rsel;

    // ---- 1. load hidden[b] (4096 f32) into LDS, float4 vectorized ----
    const float* hb = hidden + (size_t)b * 4096;
    #pragma unroll
    for (int c = 0; c < 4; ++c) {
        int base = c * 1024 + tid * 4;
        *reinterpret_cast<float4*>(&s_hid[base]) =
            *reinterpret_cast<const float4*>(hb + base);
    }
    __syncthreads();

    // ---- 1.5 h_mean ----
    #pragma unroll
    for (int r = 0; r < 2; ++r) {
        int h = r * 256 + tid;
        float s = 0.f;
        #pragma unroll
        for (int v = 0; v < 8; ++v) s += s_hid[v * 512 + h];
        s_hmean[h] = s * 0.125f;
    }

    // ---- 2. q/k projection: weight-reuse across v, K-sliced 16-way ----
    // thread = qk(2) x dgroup(8) x slice(16); h = i*16 + slice (stride-16
    // interleave -> the 8 s_hid reads per iter hit 16 consecutive addrs,
    // 4-way broadcast, conflict-free). One float4 weight load per iter,
    // reused for all 8 v. Butterfly-reduce the 16 slices in-register.
    {
        const int qk = tid >> 7;          // waves 0-1: q, waves 2-3: k
        const int dg = (tid >> 4) & 7;    // d-group (4 cols)
        const int sl = tid & 15;          // K-slice
        const float* __restrict__ W = qk ? Wk : Wq;
        const float* wp = W + dg * 4;
        float ax[8], ay[8], az[8], aw[8];
        #pragma unroll
        for (int v = 0; v < 8; ++v) { ax[v] = ay[v] = az[v] = aw[v] = 0.f; }
        for (int i = 0; i < 32; ++i) {
            int h = i * 16 + sl;
            float4 w = *reinterpret_cast<const float4*>(wp + h * 32);
            #pragma unroll
            for (int v = 0; v < 8; ++v) {
                float x = s_hid[v * 512 + h];
                ax[v] += x * w.x; ay[v] += x * w.y;
                az[v] += x * w.z; aw[v] += x * w.w;
            }
        }
        #pragma unroll
        for (int off = 1; off < 16; off <<= 1) {
            #pragma unroll
            for (int v = 0; v < 8; ++v) {
                ax[v] += __shfl_xor(ax[v], off);
                ay[v] += __shfl_xor(ay[v], off);
                az[v] += __shfl_xor(az[v], off);
                aw[v] += __shfl_xor(aw[v], off);
            }
        }
        if (sl == 0) {
            const float* bias = (qk ? bk : bq) + dg * 4;
            const float bx = bias[0], by = bias[1], bz = bias[2], bw = bias[3];
            float* dst = (qk ? &s_k[0][0] : &s_q[0][0]) + dg * 4;
            #pragma unroll
            for (int v = 0; v < 8; ++v) {
                float4 r;
                r.x = ax[v] + bx; r.y = ay[v] + by;
                r.z = az[v] + bz; r.w = aw[v] + bw;
                *reinterpret_cast<float4*>(dst + v * 32) = r;
            }
        }
    }
    __syncthreads();

    // ---- 3. scores + gumbel + 64-way argmax (wave 0) ----
    if (tid < 64) {
        int i = tid >> 3, j = tid & 7;
        float s = 0.f;
        #pragma unroll
        for (int d = 0; d < 32; ++d) s += s_q[i][d] * s_k[j][d];
        s /= TEMP;
        float u = u_var[(size_t)b * 64 + tid];
        float g = -logf(-logf(u + EPSG) + EPSG);
        float p = s + g;
        int idx = tid;
        #pragma unroll
        for (int off = 32; off >= 1; off >>= 1) {
            float pv = __shfl_xor(p, off);
            int   pi = __shfl_xor(idx, off);
            if (pv > p || (pv == p && pi < idx)) { p = pv; idx = pi; }
        }
        if (tid == 0) s_sel = idx;
    }
    __syncthreads();
    const int msel = s_sel;
    const int isel = msel >> 3;   // context variable index (i)
    const int jsel = msel & 7;    // primary variable index (j)
    const float* hp = &s_hid[jsel * 512];
    const float* hc = &s_hid[isel * 512];

    // ---- 4. q2 = concat(h_p, h_c, h_mean) @ Wq2 + bq2 (float4 weights) ----
    {
        const int dgq = tid >> 5;         // 0..7
        const int seg = tid & 31;         // 0..31
        const float* wp = Wq2 + dgq * 4;
        float a0 = 0.f, a1 = 0.f, a2 = 0.f, a3 = 0.f;
        for (int i = 0; i < 16; ++i) {
            int t = i * 32 + seg;
            float x = hp[t];
            float4 w = *reinterpret_cast<const float4*>(wp + t * 32);
            a0 += x * w.x; a1 += x * w.y; a2 += x * w.z; a3 += x * w.w;
        }
        for (int i = 16; i < 32; ++i) {
            int t = i * 32 + seg;
            float x = hc[t - 512];
            float4 w = *reinterpret_cast<const float4*>(wp + t * 32);
            a0 += x * w.x; a1 += x * w.y; a2 += x * w.z; a3 += x * w.w;
        }
        for (int i = 32; i < 48; ++i) {
            int t = i * 32 + seg;
            float x = s_hmean[t - 1024];
            float4 w = *reinterpret_cast<const float4*>(wp + t * 32);
            a0 += x * w.x; a1 += x * w.y; a2 += x * w.z; a3 += x * w.w;
        }
        #pragma unroll
        for (int off = 1; off < 32; off <<= 1) {
            a0 += __shfl_xor(a0, off);
            a1 += __shfl_xor(a1, off);
            a2 += __shfl_xor(a2, off);
            a3 += __shfl_xor(a3, off);
        }
        if (seg == 0) {
            const float* bb = bq2 + dgq * 4;
            float4 r;
            r.x = a0 + bb[0]; r.y = a1 + bb[1];
            r.z = a2 + bb[2]; r.w = a3 + bb[3];
            *reinterpret_cast<float4*>(&s_q2[dgq * 4]) = r;
        }
    }
    __syncthreads();

    // ---- 5. rule scores + gumbel + 16-way argmax (lanes 0..15) ----
    if (tid < 16) {
        float s = 0.f;
        #pragma unroll
        for (int d = 0; d < 32; ++d) s += s_q2[d] * k2[tid * 32 + d];
        s /= TEMP;
        float u = u_rule[(size_t)b * 16 + tid];
        float g = -logf(-logf(u + EPSG) + EPSG);
        float p = s + g;
        int idx = tid;
        #pragma unroll
        for (int off = 8; off >= 1; off >>= 1) {
            float pv = __shfl_xor(p, off, 16);
            int   pi = __shfl_xor(idx, off, 16);
            if (pv > p || (pv == p && pi < idx)) { p = pv; idx = pi; }
        }
        if (tid == 0) s_rsel = idx;
    }
    __syncthreads();
    const int rsel = s_rsel;

    // ---- 6. h1 = relu(concat(h_p,h_c) @ W1[rsel]) (float4 weights) ----
    {
        const int eg  = tid >> 6;         // 0..3 (= wave id)
        const int seg = tid & 63;         // lane
        const float* w1 = W1 + (size_t)rsel * 16384 + eg * 4;
        float a0 = 0.f, a1 = 0.f, a2 = 0.f, a3 = 0.f;
        for (int i = 0; i < 8; ++i) {
            int t = i * 64 + seg;
            float x = hp[t];
            float4 w = *reinterpret_cast<const float4*>(w1 + t * 16);
            a0 += x * w.x; a1 += x * w.y; a2 += x * w.z; a3 += x * w.w;
        }
        for (int i = 8; i < 16; ++i) {
            int t = i * 64 + seg;
            float x = hc[t - 512];
            float4 w = *reinterpret_cast<const float4*>(w1 + t * 16);
            a0 += x * w.x; a1 += x * w.y; a2 += x * w.z; a3 += x * w.w;
        }
        #pragma unroll
        for (int off = 1; off < 64; off <<= 1) {
            a0 += __shfl_xor(a0, off);
            a1 += __shfl_xor(a1, off);
            a2 += __shfl_xor(a2, off);
            a3 += __shfl_xor(a3, off);
        }
        if (seg == 0) {
            float4 r;
            r.x = fmaxf(a0, 0.f); r.y = fmaxf(a1, 0.f);
            r.z = fmaxf(a2, 0.f); r.w = fmaxf(a3, 0.f);
            *reinterpret_cast<float4*>(&s_h1[eg * 4]) = r;
        }
    }
    __syncthreads();

    // ---- 7. rout = h1 @ W2[rsel]; scatter to slot v == jsel (f32 out) ----
    {
        const float* w2 = W2 + (size_t)rsel * 16 * 512;
        int o0 = tid * 2;
        float a0 = 0.f, a1 = 0.f;
        #pragma unroll
        for (int e = 0; e < 16; ++e) {
            float h1e = s_h1[e];
            float2 ww = *reinterpret_cast<const float2*>(w2 + e * 512 + o0);
            a0 += h1e * ww.x;
            a1 += h1e * ww.y;
        }
        float2 nz = make_float2(a0, a1);
        float2 zz = make_float2(0.f, 0.f);
        float2* ob = reinterpret_cast<float2*>(out + (size_t)b * 4096);
        #pragma unroll
        for (int v = 0; v < 8; ++v) {
            ob[v * 256 + tid] = (v == jsel) ? nz : zz;
        }
    }
}

extern "C" void kernel_launch(void* const* d_in, const int* in_sizes, int n_in,
                              void* d_out, int out_size, void* d_ws, size_t ws_size,
                              hipStream_t stream) {
    const float* hidden   = (const float*)d_in[0];
    const float* u_var    = (const float*)d_in[1];
    const float* u_rule   = (const float*)d_in[2];
    const float* Wq       = (const float*)d_in[3];
    const float* bq       = (const float*)d_in[4];
    const float* Wk       = (const float*)d_in[5];
    const float* bk       = (const float*)d_in[6];
    const float* rule_emb = (const float*)d_in[7];
    const float* Wq2      = (const float*)d_in[8];
    const float* bq2      = (const float*)d_in[9];
    const float* Wk2      = (const float*)d_in[10];
    const float* bk2      = (const float*)d_in[11];
    const float* W1       = (const float*)d_in[12];
    const float* W2       = (const float*)d_in[13];

    float* k2 = (float*)d_ws;   // 16*32 f32

    hipLaunchKernelGGL(k2_kernel, dim3(1), dim3(512), 0, stream,
                       rule_emb, Wk2, bk2, k2);
    hipLaunchKernelGGL(rulenet_kernel, dim3(4096), dim3(256), 0, stream,
                       hidden, u_var, u_rule, Wq, bq, Wk, bk,
                       Wq2, bq2, W1, W2, k2, (float*)d_out);
}

// Round 5
// 148.001 us; speedup vs baseline: 1.3023x; 1.2517x over previous
//
#include <hip/hip_runtime.h>

#define TEMP 5.656854249492380195f   // sqrt(32)
#define EPSG 1e-10f

// ---------- K0: k2[r][d] = rule_emb[r]@Wk2[:,d] + bk2[d]; zero counters ----
__global__ void k0_kernel(const float* __restrict__ rule_emb,
                          const float* __restrict__ Wk2,
                          const float* __restrict__ bk2,
                          float* __restrict__ k2f,
                          int* __restrict__ cnt) {
    int t = threadIdx.x;              // 512 threads
    if (t < 16) cnt[t] = 0;
    int r = t >> 5, d = t & 31;
    float acc = bk2[d];
    for (int h = 0; h < 64; ++h)
        acc += rule_emb[r * 64 + h] * Wk2[h * 32 + d];
    k2f[t] = acc;
}

// ---------- K1: q/k projection (weights in VGPRs), argmax sel, hmean -------
__launch_bounds__(256, 2)
__global__ void k1_kernel(const float* __restrict__ hidden,
                          const float* __restrict__ u_var,
                          const float* __restrict__ Wq,
                          const float* __restrict__ bq,
                          const float* __restrict__ Wk,
                          const float* __restrict__ bk,
                          int* __restrict__ selbuf,
                          float* __restrict__ outbuf) {
    const int tid = threadIdx.x;
    const int b0  = blockIdx.x * 8;

    __shared__ float sh[2][4096];            // hidden double buffer (32 KB)
    __shared__ float s_qk[2][2][8][32];      // [buf][q/k][v][d]

    const int qk = tid >> 7;                 // 0: q, 1: k
    const int dg = (tid >> 4) & 7;           // 4-col group
    const int sl = tid & 15;                 // K-slice (4 h each per i)

    // resident weights: w[i][j] = W[i*64 + sl*4 + j][dg*4 .. +3]
    const float* Wsrc = (qk ? Wk : Wq) + dg * 4;
    float4 w[8][4];
    #pragma unroll
    for (int i = 0; i < 8; ++i)
        #pragma unroll
        for (int j = 0; j < 4; ++j)
            w[i][j] = *reinterpret_cast<const float4*>(Wsrc + (i * 64 + sl * 4 + j) * 32);
    const float* bsrc = (qk ? bk : bq) + dg * 4;
    float4 bias4 = *reinterpret_cast<const float4*>(bsrc);

    // prologue: stage b0 into sh[0]
    {
        const float* hb = hidden + (size_t)b0 * 4096;
        #pragma unroll
        for (int c = 0; c < 4; ++c)
            *reinterpret_cast<float4*>(&sh[0][c * 1024 + tid * 4]) =
                *reinterpret_cast<const float4*>(hb + c * 1024 + tid * 4);
    }
    __syncthreads();

    for (int bb = 0; bb < 8; ++bb) {
        const int p = bb & 1;
        const int b = b0 + bb;
        const bool hasnext = (bb < 7);

        // issue prefetch for b+1 (lands during compute)
        float4 pf0, pf1, pf2, pf3;
        if (hasnext) {
            const float* hn = hidden + (size_t)(b + 1) * 4096;
            pf0 = *reinterpret_cast<const float4*>(hn + 0 * 1024 + tid * 4);
            pf1 = *reinterpret_cast<const float4*>(hn + 1 * 1024 + tid * 4);
            pf2 = *reinterpret_cast<const float4*>(hn + 2 * 1024 + tid * 4);
            pf3 = *reinterpret_cast<const float4*>(hn + 3 * 1024 + tid * 4);
        }

        // projection: acc[v] = 4 cols for all 8 v
        float4 acc[8];
        #pragma unroll
        for (int v = 0; v < 8; ++v) acc[v] = make_float4(0.f, 0.f, 0.f, 0.f);
        #pragma unroll
        for (int i = 0; i < 8; ++i) {
            float4 xv[8];
            #pragma unroll
            for (int v = 0; v < 8; ++v)
                xv[v] = *reinterpret_cast<const float4*>(&sh[p][v * 512 + i * 64 + sl * 4]);
            #pragma unroll
            for (int v = 0; v < 8; ++v) {
                acc[v].x += xv[v].x * w[i][0].x + xv[v].y * w[i][1].x + xv[v].z * w[i][2].x + xv[v].w * w[i][3].x;
                acc[v].y += xv[v].x * w[i][0].y + xv[v].y * w[i][1].y + xv[v].z * w[i][2].y + xv[v].w * w[i][3].y;
                acc[v].z += xv[v].x * w[i][0].z + xv[v].y * w[i][1].z + xv[v].z * w[i][2].z + xv[v].w * w[i][3].z;
                acc[v].w += xv[v].x * w[i][0].w + xv[v].y * w[i][1].w + xv[v].z * w[i][2].w + xv[v].w * w[i][3].w;
            }
        }
        // reduce 16 slices
        #pragma unroll
        for (int off = 1; off < 16; off <<= 1) {
            #pragma unroll
            for (int v = 0; v < 8; ++v) {
                acc[v].x += __shfl_xor(acc[v].x, off);
                acc[v].y += __shfl_xor(acc[v].y, off);
                acc[v].z += __shfl_xor(acc[v].z, off);
                acc[v].w += __shfl_xor(acc[v].w, off);
            }
        }
        if (sl == 0) {
            #pragma unroll
            for (int v = 0; v < 8; ++v) {
                float4 r;
                r.x = acc[v].x + bias4.x; r.y = acc[v].y + bias4.y;
                r.z = acc[v].z + bias4.z; r.w = acc[v].w + bias4.w;
                *reinterpret_cast<float4*>(&s_qk[p][qk][v][dg * 4]) = r;
            }
        }
        // hmean -> outbuf[b][0..511] (scratch; K3 overwrites all of out later)
        {
            int h2 = tid * 2;
            float m0 = 0.f, m1 = 0.f;
            #pragma unroll
            for (int v = 0; v < 8; ++v) {
                float2 x2 = *reinterpret_cast<const float2*>(&sh[p][v * 512 + h2]);
                m0 += x2.x; m1 += x2.y;
            }
            float2 mo; mo.x = m0 * 0.125f; mo.y = m1 * 0.125f;
            *reinterpret_cast<float2*>(outbuf + (size_t)b * 4096 + h2) = mo;
        }
        // write prefetched tile
        if (hasnext) {
            *reinterpret_cast<float4*>(&sh[p ^ 1][0 * 1024 + tid * 4]) = pf0;
            *reinterpret_cast<float4*>(&sh[p ^ 1][1 * 1024 + tid * 4]) = pf1;
            *reinterpret_cast<float4*>(&sh[p ^ 1][2 * 1024 + tid * 4]) = pf2;
            *reinterpret_cast<float4*>(&sh[p ^ 1][3 * 1024 + tid * 4]) = pf3;
        }
        __syncthreads();
        // wave 0: scores + gumbel + argmax -> selbuf[b]
        if (tid < 64) {
            int i = tid >> 3, j = tid & 7;
            float s = 0.f;
            #pragma unroll
            for (int d4 = 0; d4 < 8; ++d4) {
                float4 qv = *reinterpret_cast<const float4*>(&s_qk[p][0][i][d4 * 4]);
                float4 kv = *reinterpret_cast<const float4*>(&s_qk[p][1][j][d4 * 4]);
                s += qv.x * kv.x + qv.y * kv.y + qv.z * kv.z + qv.w * kv.w;
            }
            s /= TEMP;
            float u = u_var[(size_t)b * 64 + tid];
            float g = -logf(-logf(u + EPSG) + EPSG);
            float pm = s + g;
            int idx = tid;
            #pragma unroll
            for (int off = 32; off >= 1; off >>= 1) {
                float pv = __shfl_xor(pm, off);
                int   pi = __shfl_xor(idx, off);
                if (pv > pm || (pv == pm && pi < idx)) { pm = pv; idx = pi; }
            }
            if (tid == 0) selbuf[b] = idx;
        }
    }
}

// ---------- K2: q2 GEMM + rule gumbel argmax + rule buckets ----------------
__launch_bounds__(256, 4)
__global__ void k2sel_kernel(const float* __restrict__ hidden,
                             const float* __restrict__ u_rule,
                             const float* __restrict__ Wq2,
                             const float* __restrict__ bq2,
                             const float* __restrict__ k2f,
                             const int* __restrict__ selbuf,
                             const float* __restrict__ hmeanbuf,
                             int* __restrict__ cnt,
                             int* __restrict__ list) {
    const int tid = threadIdx.x;
    const int b0 = blockIdx.x * 8;

    __shared__ float  s_k2[512];
    __shared__ float  xt[8][256];
    __shared__ float4 part4[4][8][8];
    __shared__ float  s_q2[8][32];
    __shared__ int    s_sel8[8];

    s_k2[tid]       = k2f[tid];
    s_k2[tid + 256] = k2f[tid + 256];
    if (tid < 8) s_sel8[tid] = selbuf[b0 + tid];
    __syncthreads();

    const int d4 = tid & 7, s = tid >> 3;
    float4 acc[8];
    #pragma unroll
    for (int bb = 0; bb < 8; ++bb) acc[bb] = make_float4(0.f, 0.f, 0.f, 0.f);

    for (int kt = 0; kt < 6; ++kt) {
        float4 w[8];
        #pragma unroll
        for (int j = 0; j < 8; ++j)
            w[j] = *reinterpret_cast<const float4*>(Wq2 + (size_t)(kt * 256 + s * 8 + j) * 32 + d4 * 4);
        #pragma unroll
        for (int bb = 0; bb < 8; ++bb) {
            const int b  = b0 + bb;
            const int sv = s_sel8[bb];
            const float* src;
            if (kt < 2)      src = hidden  + ((size_t)b * 8 + (sv & 7))  * 512 + kt * 256;
            else if (kt < 4) src = hidden  + ((size_t)b * 8 + (sv >> 3)) * 512 + (kt - 2) * 256;
            else             src = hmeanbuf + (size_t)b * 4096 + (kt - 4) * 256;
            xt[bb][tid] = src[tid];
        }
        __syncthreads();
        #pragma unroll
        for (int bb = 0; bb < 8; ++bb) {
            #pragma unroll
            for (int j = 0; j < 8; ++j) {
                float x = xt[bb][s * 8 + j];
                acc[bb].x += x * w[j].x;
                acc[bb].y += x * w[j].y;
                acc[bb].z += x * w[j].z;
                acc[bb].w += x * w[j].w;
            }
        }
        __syncthreads();
    }
    // reduce over the wave's 8 s-values
    #pragma unroll
    for (int off = 8; off < 64; off <<= 1) {
        #pragma unroll
        for (int bb = 0; bb < 8; ++bb) {
            acc[bb].x += __shfl_xor(acc[bb].x, off);
            acc[bb].y += __shfl_xor(acc[bb].y, off);
            acc[bb].z += __shfl_xor(acc[bb].z, off);
            acc[bb].w += __shfl_xor(acc[bb].w, off);
        }
    }
    if ((s & 7) == 0) {
        #pragma unroll
        for (int bb = 0; bb < 8; ++bb) part4[tid >> 6][bb][d4] = acc[bb];
    }
    __syncthreads();
    {
        const int bb = tid >> 5, col = tid & 31;
        float q2 = bq2[col];
        #pragma unroll
        for (int wv = 0; wv < 4; ++wv) {
            const float* pf = reinterpret_cast<const float*>(&part4[wv][bb][col >> 2]);
            q2 += pf[col & 3];
        }
        s_q2[bb][col] = q2;
    }
    __syncthreads();
    if (tid < 128) {
        const int bb = tid >> 4, r = tid & 15;
        const int b = b0 + bb;
        float sc = 0.f;
        #pragma unroll
        for (int d = 0; d < 32; ++d) sc += s_q2[bb][d] * s_k2[r * 32 + d];
        sc /= TEMP;
        float u = u_rule[(size_t)b * 16 + r];
        float g = -logf(-logf(u + EPSG) + EPSG);
        float pm = sc + g;
        int idx = r;
        #pragma unroll
        for (int off = 8; off >= 1; off >>= 1) {
            float pv = __shfl_xor(pm, off, 16);
            int   pi = __shfl_xor(idx, off, 16);
            if (pv > pm || (pv == pm && pi < idx)) { pm = pv; idx = pi; }
        }
        if (r == 0) {
            int pos = atomicAdd(&cnt[idx], 1);
            list[idx * 4096 + pos] = b;
        }
    }
}

// ---------- K3: rule-bucketed MLP + full output write ----------------------
__launch_bounds__(256, 2)
__global__ void k3_kernel(const float* __restrict__ hidden,
                          const float* __restrict__ W1,
                          const float* __restrict__ W2,
                          const int* __restrict__ selbuf,
                          const int* __restrict__ cnt,
                          const int* __restrict__ list,
                          float* __restrict__ outbuf) {
    const int tid = threadIdx.x;
    const int r   = blockIdx.x & 15;       // rule
    const int c   = blockIdx.x >> 4;       // chunk 0..31

    __shared__ float w1s[16384];           // W1[r] as [row*16+e] (64 KB)
    __shared__ float comb[1024];
    __shared__ float part[4][16];
    __shared__ float s_h1[16];

    #pragma unroll
    for (int i = 0; i < 16; ++i) {
        int idx = i * 1024 + tid * 4;
        *reinterpret_cast<float4*>(&w1s[idx]) =
            *reinterpret_cast<const float4*>(W1 + (size_t)r * 16384 + idx);
    }
    const int n = cnt[r];
    __syncthreads();

    const int e  = tid & 15;
    const int sl = tid >> 4;

    for (int idx = c; idx < n; idx += 32) {
        const int b  = list[r * 4096 + idx];
        const int sv = selbuf[b];
        const int js = sv & 7, cs = sv >> 3;

        // stage comb = [h_p | h_c]
        {
            const float4* h4 = reinterpret_cast<const float4*>(hidden);
            float4 v;
            if (tid < 128) v = h4[((size_t)b * 8 + js) * 128 + tid];
            else           v = h4[((size_t)b * 8 + cs) * 128 + (tid - 128)];
            *reinterpret_cast<float4*>(&comb[tid * 4]) = v;
        }
        __syncthreads();

        // h1 partials: thread (e, sl) covers rows == sl (mod 16)
        float a = 0.f;
        for (int i = 0; i < 64; ++i) {
            int rr = i * 16 + sl;
            a += comb[rr] * w1s[rr * 16 + e];
        }
        a += __shfl_xor(a, 16);
        a += __shfl_xor(a, 32);
        if ((sl & 3) == 0) part[sl >> 2][e] = a;
        __syncthreads();
        if (tid < 16)
            s_h1[tid] = fmaxf(part[0][tid] + part[1][tid] + part[2][tid] + part[3][tid], 0.f);
        __syncthreads();

        // rout + scatter/zero-fill write of all 8 slots
        const float* w2 = W2 + (size_t)r * 8192;
        int o0 = tid * 2;
        float a0 = 0.f, a1 = 0.f;
        #pragma unroll
        for (int ee = 0; ee < 16; ++ee) {
            float h1e = s_h1[ee];
            float2 ww = *reinterpret_cast<const float2*>(w2 + ee * 512 + o0);
            a0 += h1e * ww.x;
            a1 += h1e * ww.y;
        }
        float2 nz = make_float2(a0, a1);
        float2 zz = make_float2(0.f, 0.f);
        float2* ob = reinterpret_cast<float2*>(outbuf + (size_t)b * 4096);
        #pragma unroll
        for (int v = 0; v < 8; ++v)
            ob[v * 256 + tid] = (v == js) ? nz : zz;
    }
}

extern "C" void kernel_launch(void* const* d_in, const int* in_sizes, int n_in,
                              void* d_out, int out_size, void* d_ws, size_t ws_size,
                              hipStream_t stream) {
    const float* hidden   = (const float*)d_in[0];
    const float* u_var    = (const float*)d_in[1];
    const float* u_rule   = (const float*)d_in[2];
    const float* Wq       = (const float*)d_in[3];
    const float* bq       = (const float*)d_in[4];
    const float* Wk       = (const float*)d_in[5];
    const float* bk       = (const float*)d_in[6];
    const float* rule_emb = (const float*)d_in[7];
    const float* Wq2      = (const float*)d_in[8];
    const float* bq2      = (const float*)d_in[9];
    const float* Wk2      = (const float*)d_in[10];
    const float* bk2      = (const float*)d_in[11];
    const float* W1       = (const float*)d_in[12];
    const float* W2       = (const float*)d_in[13];

    char* ws = (char*)d_ws;
    float* k2f  = (float*)(ws);              // 512 f32
    int*   cnt  = (int*)(ws + 2048);         // 16 i32
    int*   sel  = (int*)(ws + 4096);         // 4096 i32
    int*   list = (int*)(ws + 20480);        // 16*4096 i32
    float* outf = (float*)d_out;

    hipLaunchKernelGGL(k0_kernel, dim3(1), dim3(512), 0, stream,
                       rule_emb, Wk2, bk2, k2f, cnt);
    hipLaunchKernelGGL(k1_kernel, dim3(512), dim3(256), 0, stream,
                       hidden, u_var, Wq, bq, Wk, bk, sel, outf);
    hipLaunchKernelGGL(k2sel_kernel, dim3(512), dim3(256), 0, stream,
                       hidden, u_rule, Wq2, bq2, k2f, sel, outf, cnt, list);
    hipLaunchKernelGGL(k3_kernel, dim3(512), dim3(256), 0, stream,
                       hidden, W1, W2, sel, cnt, list, outf);
}